// Round 4
// baseline (994.649 us; speedup 1.0000x reference)
//
#include <hip/hip_runtime.h>
#include <hip/hip_fp16.h>
#include <math.h>

#define VOLN 256
#define N_ANG 16
#define DET_V 128
#define DET_U 128
#define DET_SP 5.0
#define DSI 400.0
#define DSD 800.0
#define N_STEP 192

// radius = sqrt(3)*256/2 ; t0 = DSI - radius ; dt = 2*radius/N_STEP
#define T0_F 178.29749663118372f
#define DT_F 2.3094010767585029f

// ---------------- fp32 -> fp16 volume conversion (into d_ws) ----------------
__global__ __launch_bounds__(256) void cvt_fp16_kernel(const float4* __restrict__ in,
                                                       uint2* __restrict__ out) {
    const int n4 = (VOLN * VOLN * VOLN) / 4;
    int stride = gridDim.x * blockDim.x;
    for (int i = blockIdx.x * blockDim.x + threadIdx.x; i < n4; i += stride) {
        float4 f = in[i];
        __half2 a = __floats2half2_rn(f.x, f.y);
        __half2 b = __floats2half2_rn(f.z, f.w);
        uint2 o;
        o.x = *reinterpret_cast<const unsigned int*>(&a);
        o.y = *reinterpret_cast<const unsigned int*>(&b);
        out[i] = o;
    }
}

// ---------------- fp16 trilerp ----------------
__device__ __forceinline__ float trilerp_h(const __half* __restrict__ vol,
                                           float pz, float py, float px) {
    float z0f = floorf(pz), y0f = floorf(py), x0f = floorf(px);
    int z0 = (int)z0f, y0 = (int)y0f, x0 = (int)x0f;
    float fz = pz - z0f, fy = py - y0f, fx = px - x0f;

    if (z0 >= 0 && z0 <= VOLN - 2 && y0 >= 0 && y0 <= VOLN - 2 && x0 >= 0 && x0 <= VOLN - 2) {
        const __half* base = vol + (((z0 << 8) + y0) << 8) + x0;
        float v000 = __half2float(base[0]);
        float v001 = __half2float(base[1]);
        float v010 = __half2float(base[VOLN]);
        float v011 = __half2float(base[VOLN + 1]);
        float v100 = __half2float(base[VOLN * VOLN]);
        float v101 = __half2float(base[VOLN * VOLN + 1]);
        float v110 = __half2float(base[VOLN * VOLN + VOLN]);
        float v111 = __half2float(base[VOLN * VOLN + VOLN + 1]);
        float c00 = fmaf(fx, v001 - v000, v000);
        float c01 = fmaf(fx, v011 - v010, v010);
        float c10 = fmaf(fx, v101 - v100, v100);
        float c11 = fmaf(fx, v111 - v110, v110);
        float c0 = fmaf(fy, c01 - c00, c00);
        float c1 = fmaf(fy, c11 - c10, c10);
        return fmaf(fz, c1 - c0, c0);
    }

    if (z0 < -1 || z0 > VOLN - 1 || y0 < -1 || y0 > VOLN - 1 || x0 < -1 || x0 > VOLN - 1)
        return 0.0f;

    float acc = 0.0f;
    #pragma unroll
    for (int dz = 0; dz < 2; ++dz) {
        int iz = z0 + dz;
        if (iz < 0 || iz > VOLN - 1) continue;
        float wz = dz ? fz : (1.0f - fz);
        #pragma unroll
        for (int dy = 0; dy < 2; ++dy) {
            int iy = y0 + dy;
            if (iy < 0 || iy > VOLN - 1) continue;
            float wy = dy ? fy : (1.0f - fy);
            #pragma unroll
            for (int dx = 0; dx < 2; ++dx) {
                int ix = x0 + dx;
                if (ix < 0 || ix > VOLN - 1) continue;
                float wx = dx ? fx : (1.0f - fx);
                float v = __half2float(vol[(((iz << 8) + iy) << 8) + ix]);
                acc = fmaf(wz * wy * wx, v, acc);
            }
        }
    }
    return acc;
}

// ---------------- fp32 trilerp (fallback) ----------------
__device__ __forceinline__ float trilerp_f(const float* __restrict__ vol,
                                           float pz, float py, float px) {
    float z0f = floorf(pz), y0f = floorf(py), x0f = floorf(px);
    int z0 = (int)z0f, y0 = (int)y0f, x0 = (int)x0f;
    float fz = pz - z0f, fy = py - y0f, fx = px - x0f;

    if (z0 >= 0 && z0 <= VOLN - 2 && y0 >= 0 && y0 <= VOLN - 2 && x0 >= 0 && x0 <= VOLN - 2) {
        const float* base = vol + (((z0 << 8) + y0) << 8) + x0;
        float v000 = base[0], v001 = base[1];
        float v010 = base[VOLN], v011 = base[VOLN + 1];
        float v100 = base[VOLN * VOLN], v101 = base[VOLN * VOLN + 1];
        float v110 = base[VOLN * VOLN + VOLN], v111 = base[VOLN * VOLN + VOLN + 1];
        float c00 = fmaf(fx, v001 - v000, v000);
        float c01 = fmaf(fx, v011 - v010, v010);
        float c10 = fmaf(fx, v101 - v100, v100);
        float c11 = fmaf(fx, v111 - v110, v110);
        float c0 = fmaf(fy, c01 - c00, c00);
        float c1 = fmaf(fy, c11 - c10, c10);
        return fmaf(fz, c1 - c0, c0);
    }
    if (z0 < -1 || z0 > VOLN - 1 || y0 < -1 || y0 > VOLN - 1 || x0 < -1 || x0 > VOLN - 1)
        return 0.0f;
    float acc = 0.0f;
    #pragma unroll
    for (int dz = 0; dz < 2; ++dz) {
        int iz = z0 + dz;
        if (iz < 0 || iz > VOLN - 1) continue;
        float wz = dz ? fz : (1.0f - fz);
        #pragma unroll
        for (int dy = 0; dy < 2; ++dy) {
            int iy = y0 + dy;
            if (iy < 0 || iy > VOLN - 1) continue;
            float wy = dy ? fy : (1.0f - fy);
            #pragma unroll
            for (int dx = 0; dx < 2; ++dx) {
                int ix = x0 + dx;
                if (ix < 0 || ix > VOLN - 1) continue;
                float wx = dx ? fx : (1.0f - fx);
                acc = fmaf(wz * wy * wx, vol[(((iz << 8) + iy) << 8) + ix], acc);
            }
        }
    }
    return acc;
}

// ---------------- ray setup ----------------
struct Ray { float dirz, diry, dirx, bz, by, bx; };

__device__ __forceinline__ Ray make_ray(int a, int u, int v) {
    double theta = (2.0 * M_PI / (double)N_ANG) * (double)a;
    double cth = cos(theta), sth = sin(theta);
    double uoff = ((double)u - (DET_U - 1) * 0.5) * DET_SP;
    double voff = ((double)v - (DET_V - 1) * 0.5) * DET_SP;

    double dzd = voff;
    double dyd = -DSD * sth + uoff * cth;
    double dxd = -DSD * cth - uoff * sth;
    double inv = 1.0 / sqrt(uoff * uoff + voff * voff + DSD * DSD);

    Ray r;
    r.dirz = (float)(dzd * inv);
    r.diry = (float)(dyd * inv);
    r.dirx = (float)(dxd * inv);
    const float half = (VOLN - 1) * 0.5f;
    r.bz = 0.0f + half;
    r.by = (float)(DSI * sth) + half;
    r.bx = (float)(DSI * cth) + half;
    return r;
}

// XCD-aware block mapping: xcd = blockIdx.x % 8 (HW round-robin). Each XCD gets
// exactly 2 angles {k, k+8}; within an angle, blocks cover v-row pairs in order,
// so the XCD's 4 MiB L2 holds the 1-2 live t-shell slabs of its own angles.
__device__ __forceinline__ void decode_block(int b, int tid, int& a, int& u, int& v) {
    int s = b >> 3;                    // 0..127 within-XCD sequence
    a = (b & 7) + ((s >> 6) << 3);     // angle: xcd for first 64, xcd+8 for next 64
    int vpair = s & 63;
    u = tid & 127;
    v = (vpair << 1) + (tid >> 7);
}

__global__ __launch_bounds__(256) void cone_proj_h_kernel(const __half* __restrict__ vol,
                                                          float* __restrict__ out) {
    int a, u, v;
    decode_block(blockIdx.x, threadIdx.x, a, u, v);
    Ray r = make_ray(a, u, v);

    float acc = 0.0f;
    #pragma unroll 4
    for (int i = 0; i < N_STEP; ++i) {
        float t = fmaf((float)i + 0.5f, DT_F, T0_F);
        float pz = fmaf(t, r.dirz, r.bz);
        float py = fmaf(t, r.diry, r.by);
        float px = fmaf(t, r.dirx, r.bx);
        acc += trilerp_h(vol, pz, py, px);
    }
    out[(a << 14) + (v << 7) + u] = acc * DT_F;
}

__global__ __launch_bounds__(256) void cone_proj_f_kernel(const float* __restrict__ vol,
                                                          float* __restrict__ out) {
    int a, u, v;
    decode_block(blockIdx.x, threadIdx.x, a, u, v);
    Ray r = make_ray(a, u, v);

    float acc = 0.0f;
    #pragma unroll 4
    for (int i = 0; i < N_STEP; ++i) {
        float t = fmaf((float)i + 0.5f, DT_F, T0_F);
        float pz = fmaf(t, r.dirz, r.bz);
        float py = fmaf(t, r.diry, r.by);
        float px = fmaf(t, r.dirx, r.bx);
        acc += trilerp_f(vol, pz, py, px);
    }
    out[(a << 14) + (v << 7) + u] = acc * DT_F;
}

extern "C" void kernel_launch(void* const* d_in, const int* in_sizes, int n_in,
                              void* d_out, int out_size, void* d_ws, size_t ws_size,
                              hipStream_t stream) {
    const float* vol = (const float*)d_in[0];
    float* out = (float*)d_out;
    const int total = N_ANG * DET_V * DET_U;
    const size_t need = (size_t)VOLN * VOLN * VOLN * sizeof(__half);   // 32 MiB

    if (ws_size >= need) {
        cvt_fp16_kernel<<<4096, 256, 0, stream>>>((const float4*)vol, (uint2*)d_ws);
        cone_proj_h_kernel<<<total / 256, 256, 0, stream>>>((const __half*)d_ws, out);
    } else {
        cone_proj_f_kernel<<<total / 256, 256, 0, stream>>>(vol, out);
    }
}

// Round 8
// 519.075 us; speedup vs baseline: 1.9162x; 1.9162x over previous
//
#include <hip/hip_runtime.h>
#include <hip/hip_fp16.h>
#include <math.h>

#define VOLN 256
#define N_ANG 16
#define DET_V 128
#define DET_U 128
#define DET_SP 5.0
#define DSI 400.0
#define DSD 800.0
#define N_STEP 192

// radius = sqrt(3)*256/2 ; t0 = DSI - radius ; dt = 2*radius/N_STEP
#define T0_F 178.29749663118372f
#define DT_F 2.3094010767585029f

// ---------------- fp32 -> fp16 volume conversion (into d_ws) ----------------
__global__ __launch_bounds__(256) void cvt_fp16_kernel(const float4* __restrict__ in,
                                                       uint2* __restrict__ out) {
    const int n4 = (VOLN * VOLN * VOLN) / 4;
    int stride = gridDim.x * blockDim.x;
    for (int i = blockIdx.x * blockDim.x + threadIdx.x; i < n4; i += stride) {
        float4 f = in[i];
        __half2 a = __floats2half2_rn(f.x, f.y);
        __half2 b = __floats2half2_rn(f.z, f.w);
        uint2 o;
        o.x = *reinterpret_cast<const unsigned int*>(&a);
        o.y = *reinterpret_cast<const unsigned int*>(&b);
        out[i] = o;
    }
}

// ---------------- fp16 trilerp ----------------
__device__ __forceinline__ float trilerp_h(const __half* __restrict__ vol,
                                           float pz, float py, float px) {
    float z0f = floorf(pz), y0f = floorf(py), x0f = floorf(px);
    int z0 = (int)z0f, y0 = (int)y0f, x0 = (int)x0f;
    float fz = pz - z0f, fy = py - y0f, fx = px - x0f;

    if (z0 >= 0 && z0 <= VOLN - 2 && y0 >= 0 && y0 <= VOLN - 2 && x0 >= 0 && x0 <= VOLN - 2) {
        const __half* base = vol + (((z0 << 8) + y0) << 8) + x0;
        float v000 = __half2float(base[0]);
        float v001 = __half2float(base[1]);
        float v010 = __half2float(base[VOLN]);
        float v011 = __half2float(base[VOLN + 1]);
        float v100 = __half2float(base[VOLN * VOLN]);
        float v101 = __half2float(base[VOLN * VOLN + 1]);
        float v110 = __half2float(base[VOLN * VOLN + VOLN]);
        float v111 = __half2float(base[VOLN * VOLN + VOLN + 1]);
        float c00 = fmaf(fx, v001 - v000, v000);
        float c01 = fmaf(fx, v011 - v010, v010);
        float c10 = fmaf(fx, v101 - v100, v100);
        float c11 = fmaf(fx, v111 - v110, v110);
        float c0 = fmaf(fy, c01 - c00, c00);
        float c1 = fmaf(fy, c11 - c10, c10);
        return fmaf(fz, c1 - c0, c0);
    }

    if (z0 < -1 || z0 > VOLN - 1 || y0 < -1 || y0 > VOLN - 1 || x0 < -1 || x0 > VOLN - 1)
        return 0.0f;

    float acc = 0.0f;
    #pragma unroll
    for (int dz = 0; dz < 2; ++dz) {
        int iz = z0 + dz;
        if (iz < 0 || iz > VOLN - 1) continue;
        float wz = dz ? fz : (1.0f - fz);
        #pragma unroll
        for (int dy = 0; dy < 2; ++dy) {
            int iy = y0 + dy;
            if (iy < 0 || iy > VOLN - 1) continue;
            float wy = dy ? fy : (1.0f - fy);
            #pragma unroll
            for (int dx = 0; dx < 2; ++dx) {
                int ix = x0 + dx;
                if (ix < 0 || ix > VOLN - 1) continue;
                float wx = dx ? fx : (1.0f - fx);
                float v = __half2float(vol[(((iz << 8) + iy) << 8) + ix]);
                acc = fmaf(wz * wy * wx, v, acc);
            }
        }
    }
    return acc;
}

// ---------------- fp32 trilerp (fallback) ----------------
__device__ __forceinline__ float trilerp_f(const float* __restrict__ vol,
                                           float pz, float py, float px) {
    float z0f = floorf(pz), y0f = floorf(py), x0f = floorf(px);
    int z0 = (int)z0f, y0 = (int)y0f, x0 = (int)x0f;
    float fz = pz - z0f, fy = py - y0f, fx = px - x0f;

    if (z0 >= 0 && z0 <= VOLN - 2 && y0 >= 0 && y0 <= VOLN - 2 && x0 >= 0 && x0 <= VOLN - 2) {
        const float* base = vol + (((z0 << 8) + y0) << 8) + x0;
        float v000 = base[0], v001 = base[1];
        float v010 = base[VOLN], v011 = base[VOLN + 1];
        float v100 = base[VOLN * VOLN], v101 = base[VOLN * VOLN + 1];
        float v110 = base[VOLN * VOLN + VOLN], v111 = base[VOLN * VOLN + VOLN + 1];
        float c00 = fmaf(fx, v001 - v000, v000);
        float c01 = fmaf(fx, v011 - v010, v010);
        float c10 = fmaf(fx, v101 - v100, v100);
        float c11 = fmaf(fx, v111 - v110, v110);
        float c0 = fmaf(fy, c01 - c00, c00);
        float c1 = fmaf(fy, c11 - c10, c10);
        return fmaf(fz, c1 - c0, c0);
    }
    if (z0 < -1 || z0 > VOLN - 1 || y0 < -1 || y0 > VOLN - 1 || x0 < -1 || x0 > VOLN - 1)
        return 0.0f;
    float acc = 0.0f;
    #pragma unroll
    for (int dz = 0; dz < 2; ++dz) {
        int iz = z0 + dz;
        if (iz < 0 || iz > VOLN - 1) continue;
        float wz = dz ? fz : (1.0f - fz);
        #pragma unroll
        for (int dy = 0; dy < 2; ++dy) {
            int iy = y0 + dy;
            if (iy < 0 || iy > VOLN - 1) continue;
            float wy = dy ? fy : (1.0f - fy);
            #pragma unroll
            for (int dx = 0; dx < 2; ++dx) {
                int ix = x0 + dx;
                if (ix < 0 || ix > VOLN - 1) continue;
                float wx = dx ? fx : (1.0f - fx);
                acc = fmaf(wz * wy * wx, vol[(((iz << 8) + iy) << 8) + ix], acc);
            }
        }
    }
    return acc;
}

// ---------------- ray setup ----------------
struct Ray { float dirz, diry, dirx, bz, by, bx; };

__device__ __forceinline__ Ray make_ray(int a, int u, int v) {
    double theta = (2.0 * M_PI / (double)N_ANG) * (double)a;
    double cth = cos(theta), sth = sin(theta);
    double uoff = ((double)u - (DET_U - 1) * 0.5) * DET_SP;
    double voff = ((double)v - (DET_V - 1) * 0.5) * DET_SP;

    double dzd = voff;
    double dyd = -DSD * sth + uoff * cth;
    double dxd = -DSD * cth - uoff * sth;
    double inv = 1.0 / sqrt(uoff * uoff + voff * voff + DSD * DSD);

    Ray r;
    r.dirz = (float)(dzd * inv);
    r.diry = (float)(dyd * inv);
    r.dirx = (float)(dxd * inv);
    const float half = (VOLN - 1) * 0.5f;
    r.bz = 0.0f + half;
    r.by = (float)(DSI * sth) + half;
    r.bx = (float)(DSI * cth) + half;
    return r;
}

// v-band XCD mapping. Assuming HW dispatches blockIdx round-robin across the
// 8 XCDs (xcd = b & 7): XCD k receives, for EVERY angle, the contiguous
// detector v-band [16k, 16k+16). All 16 angles stay co-resident per XCD
// (round-3's winning property) but each XCD's volume footprint becomes a
// z-localized wedge instead of the whole volume.
//   b: [xcd:3][j:7]  j = (sub:3)(angle:4)  -> v-pair = 8*xcd + sub
__device__ __forceinline__ void decode_block(int b, int tid, int& a, int& u, int& v) {
    int xcd = b & 7;
    int j = b >> 3;            // 0..127
    a = j & 15;
    int sub = j >> 4;          // 0..7
    int vpair = (xcd << 3) + sub;
    u = tid & 127;
    v = (vpair << 1) + (tid >> 7);
}

__global__ __launch_bounds__(256) void cone_proj_h_kernel(const __half* __restrict__ vol,
                                                          float* __restrict__ out) {
    int a, u, v;
    decode_block(blockIdx.x, threadIdx.x, a, u, v);
    Ray r = make_ray(a, u, v);

    float acc = 0.0f;
    #pragma unroll 4
    for (int i = 0; i < N_STEP; ++i) {
        float t = fmaf((float)i + 0.5f, DT_F, T0_F);
        float pz = fmaf(t, r.dirz, r.bz);
        float py = fmaf(t, r.diry, r.by);
        float px = fmaf(t, r.dirx, r.bx);
        acc += trilerp_h(vol, pz, py, px);
    }
    out[(a << 14) + (v << 7) + u] = acc * DT_F;
}

__global__ __launch_bounds__(256) void cone_proj_f_kernel(const float* __restrict__ vol,
                                                          float* __restrict__ out) {
    int a, u, v;
    decode_block(blockIdx.x, threadIdx.x, a, u, v);
    Ray r = make_ray(a, u, v);

    float acc = 0.0f;
    #pragma unroll 4
    for (int i = 0; i < N_STEP; ++i) {
        float t = fmaf((float)i + 0.5f, DT_F, T0_F);
        float pz = fmaf(t, r.dirz, r.bz);
        float py = fmaf(t, r.diry, r.by);
        float px = fmaf(t, r.dirx, r.bx);
        acc += trilerp_f(vol, pz, py, px);
    }
    out[(a << 14) + (v << 7) + u] = acc * DT_F;
}

extern "C" void kernel_launch(void* const* d_in, const int* in_sizes, int n_in,
                              void* d_out, int out_size, void* d_ws, size_t ws_size,
                              hipStream_t stream) {
    const float* vol = (const float*)d_in[0];
    float* out = (float*)d_out;
    const int total = N_ANG * DET_V * DET_U;
    const size_t need = (size_t)VOLN * VOLN * VOLN * sizeof(__half);   // 32 MiB

    if (ws_size >= need) {
        cvt_fp16_kernel<<<4096, 256, 0, stream>>>((const float4*)vol, (uint2*)d_ws);
        cone_proj_h_kernel<<<total / 256, 256, 0, stream>>>((const __half*)d_ws, out);
    } else {
        cone_proj_f_kernel<<<total / 256, 256, 0, stream>>>(vol, out);
    }
}